// Round 2
// baseline (387.134 us; speedup 1.0000x reference)
//
#include <hip/hip_runtime.h>
#include <math.h>

#define BLK 256

// ---------------------------------------------------------------------------
// Prep: transform ref points (x,y,z) -> (-2x, -2y, -2z, x^2+y^2+z^2) so the
// main loop's per-pair cost is 3 fma + 1 min:
//   val = fma(qx,rx', fma(qy,ry', fma(qz,rz', r2))) = |r|^2 - 2 q.r
//   dist = val + |q|^2  (added once after the min)
// Layout in ws: [0 .. 65535] transformed preds, [65536 .. 131071] transformed gts.
// ---------------------------------------------------------------------------
__global__ __launch_bounds__(BLK) void prep_kernel(
    const float* __restrict__ preds,
    const float* __restrict__ gts,
    float4* __restrict__ ws4,
    int half /* = B*N = 65536 */)
{
    int i = blockIdx.x * BLK + threadIdx.x;
    const float* src = (i < half) ? preds : gts;
    int j = (i < half) ? i : i - half;
    float x = src[j * 3 + 0];
    float y = src[j * 3 + 1];
    float z = src[j * 3 + 2];
    ws4[i] = make_float4(-2.0f * x, -2.0f * y, -2.0f * z,
                         x * x + y * y + z * z);
}

// ---------------------------------------------------------------------------
// Main: one thread per query point. Refs are wave-uniform -> the ref4[k]
// loads should scalarize to s_load_dwordx4/x16 (scalar pipe, L2-served),
// leaving the VALU pipe as the only bottleneck (4 instr/pair).
// ---------------------------------------------------------------------------
__global__ __launch_bounds__(BLK) void chamfer_main(
    const float* __restrict__ preds,
    const float* __restrict__ gts,
    const float4* __restrict__ ws4,
    float* __restrict__ out,
    int N)
{
    const int b   = blockIdx.y;
    const int dir = blockIdx.z;
    // dir 0: queries = gts (loss_2), refs = transformed preds
    // dir 1: queries = preds (loss_1), refs = transformed gts
    const float*  q = ((dir == 0) ? gts : preds) + (size_t)b * N * 3;
    const float4* r = ws4 + ((dir == 0) ? 0 : 8 * N) + (size_t)b * N;

    __shared__ float wsum[BLK / 64];

    const int tid = threadIdx.x;
    const int qi  = blockIdx.x * BLK + tid;

    const float qx = q[qi * 3 + 0];
    const float qy = q[qi * 3 + 1];
    const float qz = q[qi * 3 + 2];
    const float q2 = qx * qx + qy * qy + qz * qz;

    float b0 = 3.4e38f, b1 = 3.4e38f, b2 = 3.4e38f, b3 = 3.4e38f;

    #pragma unroll 2
    for (int k = 0; k < N; k += 4) {
        float4 r0 = r[k + 0];
        float4 r1 = r[k + 1];
        float4 r2 = r[k + 2];
        float4 r3 = r[k + 3];
        b0 = fminf(b0, fmaf(qx, r0.x, fmaf(qy, r0.y, fmaf(qz, r0.z, r0.w))));
        b1 = fminf(b1, fmaf(qx, r1.x, fmaf(qy, r1.y, fmaf(qz, r1.z, r1.w))));
        b2 = fminf(b2, fmaf(qx, r2.x, fmaf(qy, r2.y, fmaf(qz, r2.z, r2.w))));
        b3 = fminf(b3, fmaf(qx, r3.x, fmaf(qy, r3.y, fmaf(qz, r3.z, r3.w))));
    }

    float best = fminf(fminf(b0, b1), fminf(b2, b3)) + q2;

    // wave64 shuffle reduce (sum of per-query mins)
    float s = best;
    #pragma unroll
    for (int off = 32; off > 0; off >>= 1)
        s += __shfl_down(s, off, 64);

    if ((tid & 63) == 0) wsum[tid >> 6] = s;
    __syncthreads();
    if (tid == 0) {
        float tot = 0.0f;
        #pragma unroll
        for (int w = 0; w < BLK / 64; ++w) tot += wsum[w];
        atomicAdd(out, tot);
    }
}

// ---------------------------------------------------------------------------
// Fallback main (no workspace transform): raw refs, 7 VALU/pair. Used only if
// ws_size is too small for the transformed copy (2 MB needed).
// ---------------------------------------------------------------------------
__global__ __launch_bounds__(BLK) void chamfer_main_raw(
    const float* __restrict__ preds,
    const float* __restrict__ gts,
    float* __restrict__ out,
    int N)
{
    const int b   = blockIdx.y;
    const int dir = blockIdx.z;
    const float* q = ((dir == 0) ? gts   : preds) + (size_t)b * N * 3;
    const float* r = ((dir == 0) ? preds : gts)   + (size_t)b * N * 3;

    __shared__ float wsum[BLK / 64];

    const int tid = threadIdx.x;
    const int qi  = blockIdx.x * BLK + tid;

    const float qx = q[qi * 3 + 0];
    const float qy = q[qi * 3 + 1];
    const float qz = q[qi * 3 + 2];

    float b0 = 3.4e38f, b1 = 3.4e38f, b2 = 3.4e38f, b3 = 3.4e38f;

    #pragma unroll 2
    for (int k = 0; k < N; k += 4) {
        float x0 = r[(k+0)*3], y0 = r[(k+0)*3+1], z0 = r[(k+0)*3+2];
        float x1 = r[(k+1)*3], y1 = r[(k+1)*3+1], z1 = r[(k+1)*3+2];
        float x2 = r[(k+2)*3], y2 = r[(k+2)*3+1], z2 = r[(k+2)*3+2];
        float x3 = r[(k+3)*3], y3 = r[(k+3)*3+1], z3 = r[(k+3)*3+2];
        float dx, dy, dz, d;
        dx = qx - x0; dy = qy - y0; dz = qz - z0;
        d = dx*dx + dy*dy + dz*dz; b0 = fminf(b0, d);
        dx = qx - x1; dy = qy - y1; dz = qz - z1;
        d = dx*dx + dy*dy + dz*dz; b1 = fminf(b1, d);
        dx = qx - x2; dy = qy - y2; dz = qz - z2;
        d = dx*dx + dy*dy + dz*dz; b2 = fminf(b2, d);
        dx = qx - x3; dy = qy - y3; dz = qz - z3;
        d = dx*dx + dy*dy + dz*dz; b3 = fminf(b3, d);
    }

    float best = fminf(fminf(b0, b1), fminf(b2, b3));

    float s = best;
    #pragma unroll
    for (int off = 32; off > 0; off >>= 1)
        s += __shfl_down(s, off, 64);

    if ((tid & 63) == 0) wsum[tid >> 6] = s;
    __syncthreads();
    if (tid == 0) {
        float tot = 0.0f;
        #pragma unroll
        for (int w = 0; w < BLK / 64; ++w) tot += wsum[w];
        atomicAdd(out, tot);
    }
}

extern "C" void kernel_launch(void* const* d_in, const int* in_sizes, int n_in,
                              void* d_out, int out_size, void* d_ws, size_t ws_size,
                              hipStream_t stream) {
    const float* preds = (const float*)d_in[0];
    const float* gts   = (const float*)d_in[1];
    float* out = (float*)d_out;

    const int B = 8;
    const int N = 8192;
    const int half = B * N;                    // 65536 points per input
    const size_t ws_needed = (size_t)2 * half * sizeof(float4);  // 2 MB

    hipMemsetAsync(out, 0, sizeof(float), stream);

    dim3 grid(N / BLK, B, 2);
    dim3 block(BLK);

    if (ws_size >= ws_needed) {
        float4* ws4 = (float4*)d_ws;
        prep_kernel<<<dim3(2 * half / BLK), block, 0, stream>>>(preds, gts, ws4, half);
        chamfer_main<<<grid, block, 0, stream>>>(preds, gts, ws4, out, N);
    } else {
        chamfer_main_raw<<<grid, block, 0, stream>>>(preds, gts, out, N);
    }
}

// Round 3
// 149.319 us; speedup vs baseline: 2.5927x; 2.5927x over previous
//
#include <hip/hip_runtime.h>

#define BLK     256
#define QPT     8                 // queries per thread (register tile)
#define QBLK    (BLK * QPT)       // 2048 queries per block
#define SPLITS  8                 // ref-dimension split
#define N_PTS   8192
#define RCHUNK  (N_PTS / SPLITS)  // 1024 refs staged per block (16 KB LDS)

// ---------------------------------------------------------------------------
// Stage 1: each block = (query-chunk qc, ref-split s, batch b, direction dir).
// Refs transformed on the fly to (-2x,-2y,-2z,|r|^2) in LDS; one broadcast
// ds_read_b128 serves QPT*64 pairs per wave. Partial min of (|r|^2 - 2 q.r)
// combined across splits via atomicMin on order-preserving uint keys.
// ---------------------------------------------------------------------------
__global__ __launch_bounds__(BLK) void chamfer_stage1(
    const float* __restrict__ preds,
    const float* __restrict__ gts,
    unsigned int* __restrict__ minbuf /* [2][8][N_PTS] keys */)
{
    const int tid = threadIdx.x;
    const int qc  = blockIdx.x & 3;    // query chunk 0..3 (4 * 2048 = 8192)
    const int s   = blockIdx.x >> 2;   // ref split 0..7
    const int b   = blockIdx.y;
    const int dir = blockIdx.z;

    // dir 0: queries = gts (loss_2), refs = preds
    // dir 1: queries = preds (loss_1), refs = gts
    const float* q = ((dir == 0) ? gts   : preds) + (size_t)b * N_PTS * 3;
    const float* r = ((dir == 0) ? preds : gts)   + (size_t)b * N_PTS * 3;

    __shared__ float4 lds[RCHUNK];

    // stage + transform refs (coalesced stride-3 scalar loads)
    for (int t = tid; t < RCHUNK; t += BLK) {
        int ri = s * RCHUNK + t;
        float x = r[ri * 3 + 0];
        float y = r[ri * 3 + 1];
        float z = r[ri * 3 + 2];
        lds[t] = make_float4(-2.0f * x, -2.0f * y, -2.0f * z,
                             x * x + y * y + z * z);
    }

    // query register tile
    float qx[QPT], qy[QPT], qz[QPT], m[QPT];
    const int qbase = qc * QBLK + tid;
    #pragma unroll
    for (int j = 0; j < QPT; ++j) {
        int qi = qbase + j * BLK;
        qx[j] = q[qi * 3 + 0];
        qy[j] = q[qi * 3 + 1];
        qz[j] = q[qi * 3 + 2];
        m[j]  = 3.4e38f;
    }

    __syncthreads();

    #pragma unroll 2
    for (int k = 0; k < RCHUNK; ++k) {
        float4 rv = lds[k];   // broadcast ds_read_b128
        #pragma unroll
        for (int j = 0; j < QPT; ++j) {
            m[j] = fminf(m[j],
                fmaf(qx[j], rv.x, fmaf(qy[j], rv.y, fmaf(qz[j], rv.z, rv.w))));
        }
    }

    unsigned int* mb = minbuf + ((size_t)dir * 8 + b) * N_PTS;
    #pragma unroll
    for (int j = 0; j < QPT; ++j) {
        // order-preserving float->uint key (values may be negative pre-|q|^2):
        // positive: bits ^ 0x80000000 ; negative: ~bits
        unsigned int bits = __float_as_uint(m[j]);
        unsigned int key  = bits ^ ((unsigned int)((int)bits >> 31) | 0x80000000u);
        atomicMin(&mb[qbase + j * BLK], key);
    }
}

// ---------------------------------------------------------------------------
// Stage 2: decode per-query min key, add |q|^2, reduce-sum into out.
// ---------------------------------------------------------------------------
__global__ __launch_bounds__(BLK) void chamfer_stage2(
    const float* __restrict__ preds,
    const float* __restrict__ gts,
    const unsigned int* __restrict__ minbuf,
    float* __restrict__ out)
{
    __shared__ float wsum[BLK / 64];
    const int tid = threadIdx.x;
    const int g   = blockIdx.x * BLK + tid;   // 0 .. 2*8*N_PTS-1
    const int dir = g >> 16;                   // 65536 queries per direction
    const int idx = g & 65535;                 // b*N_PTS + qi

    const float* q = ((dir == 0) ? gts : preds) + (size_t)idx * 3;
    float x = q[0], y = q[1], z = q[2];

    unsigned int key  = minbuf[g];
    unsigned int bits = (key & 0x80000000u) ? (key ^ 0x80000000u) : ~key;
    float val = __uint_as_float(bits) + (x * x + y * y + z * z);

    float sv = val;
    #pragma unroll
    for (int off = 32; off > 0; off >>= 1)
        sv += __shfl_down(sv, off, 64);

    if ((tid & 63) == 0) wsum[tid >> 6] = sv;
    __syncthreads();
    if (tid == 0) {
        float tot = 0.0f;
        #pragma unroll
        for (int w = 0; w < BLK / 64; ++w) tot += wsum[w];
        atomicAdd(out, tot);
    }
}

// ---------------------------------------------------------------------------
// Fallback (ws too small): round-1 LDS-tiled kernel, 1 query/thread.
// ---------------------------------------------------------------------------
__global__ __launch_bounds__(BLK) void chamfer_fallback(
    const float* __restrict__ preds,
    const float* __restrict__ gts,
    float* __restrict__ out)
{
    const int b   = blockIdx.y;
    const int dir = blockIdx.z;
    const float* q = ((dir == 0) ? gts   : preds) + (size_t)b * N_PTS * 3;
    const float* r = ((dir == 0) ? preds : gts)   + (size_t)b * N_PTS * 3;

    __shared__ float4 lds[1024];
    __shared__ float wsum[BLK / 64];

    const int tid = threadIdx.x;
    const int qi  = blockIdx.x * BLK + tid;
    const float qx = q[qi * 3 + 0];
    const float qy = q[qi * 3 + 1];
    const float qz = q[qi * 3 + 2];
    const float q2 = qx * qx + qy * qy + qz * qz;

    float best = 3.4e38f;
    for (int t0 = 0; t0 < N_PTS; t0 += 1024) {
        __syncthreads();
        for (int t = tid; t < 1024; t += BLK) {
            int ri = t0 + t;
            float x = r[ri * 3], y = r[ri * 3 + 1], z = r[ri * 3 + 2];
            lds[t] = make_float4(-2.f * x, -2.f * y, -2.f * z, x * x + y * y + z * z);
        }
        __syncthreads();
        for (int k = 0; k < 1024; ++k) {
            float4 rv = lds[k];
            best = fminf(best, fmaf(qx, rv.x, fmaf(qy, rv.y, fmaf(qz, rv.z, rv.w))));
        }
    }
    float sv = best + q2;
    #pragma unroll
    for (int off = 32; off > 0; off >>= 1)
        sv += __shfl_down(sv, off, 64);
    if ((tid & 63) == 0) wsum[tid >> 6] = sv;
    __syncthreads();
    if (tid == 0) {
        float tot = 0.0f;
        #pragma unroll
        for (int w = 0; w < BLK / 64; ++w) tot += wsum[w];
        atomicAdd(out, tot);
    }
}

extern "C" void kernel_launch(void* const* d_in, const int* in_sizes, int n_in,
                              void* d_out, int out_size, void* d_ws, size_t ws_size,
                              hipStream_t stream) {
    const float* preds = (const float*)d_in[0];
    const float* gts   = (const float*)d_in[1];
    float* out = (float*)d_out;

    const int B = 8;
    const size_t minbuf_bytes = (size_t)2 * B * N_PTS * sizeof(unsigned int); // 512 KB

    hipMemsetAsync(out, 0, sizeof(float), stream);

    if (ws_size >= minbuf_bytes) {
        unsigned int* minbuf = (unsigned int*)d_ws;
        hipMemsetAsync(minbuf, 0xFF, minbuf_bytes, stream);  // keys = UINT_MAX

        dim3 g1(4 * SPLITS, B, 2);   // 512 blocks
        chamfer_stage1<<<g1, dim3(BLK), 0, stream>>>(preds, gts, minbuf);

        dim3 g2((2 * B * N_PTS) / BLK);  // 512 blocks
        chamfer_stage2<<<g2, dim3(BLK), 0, stream>>>(preds, gts, minbuf, out);
    } else {
        dim3 grid(N_PTS / BLK, B, 2);
        chamfer_fallback<<<grid, dim3(BLK), 0, stream>>>(preds, gts, out);
    }
}

// Round 4
// 145.928 us; speedup vs baseline: 2.6529x; 1.0232x over previous
//
#include <hip/hip_runtime.h>

#define BLK     256
#define QPT     16                // queries per thread (register tile)
#define QBLK    (BLK * QPT)       // 4096 queries per block
#define SPLITS  16                // ref-dimension split
#define N_PTS   8192
#define RCHUNK  (N_PTS / SPLITS)  // 512 refs staged per block (8 KB LDS)

typedef float v2f __attribute__((ext_vector_type(2)));
typedef float v4f __attribute__((ext_vector_type(4)));

// ---------------------------------------------------------------------------
// Stage 1: block = (query-chunk qc, ref-split s, batch b, direction dir).
// Refs transformed on the fly to (-2x,-2y,-2z,|r|^2), stored packed-SoA in
// LDS (X4/Y4/Z4/W4 as float4 = two {even,odd} pairs). Inner loop: per 4 refs
// per query = 6 v_pk_fma_f32 + 2 v_min3_f32 = 2 VALU issue slots per pair.
// Partial mins combined across splits via atomicMin on order-preserving keys.
// ---------------------------------------------------------------------------
__global__ __launch_bounds__(BLK, 2) void chamfer_stage1(
    const float* __restrict__ preds,
    const float* __restrict__ gts,
    unsigned int* __restrict__ minbuf /* [2][8][N_PTS] keys */)
{
    const int tid = threadIdx.x;
    const int qc  = blockIdx.x & 1;    // query chunk 0..1 (2 * 4096 = 8192)
    const int s   = blockIdx.x >> 1;   // ref split 0..15
    const int b   = blockIdx.y;
    const int dir = blockIdx.z;

    // dir 0: queries = gts (loss_2), refs = preds
    // dir 1: queries = preds (loss_1), refs = gts
    const float* q = ((dir == 0) ? gts   : preds) + (size_t)b * N_PTS * 3;
    const float* r = ((dir == 0) ? preds : gts)   + (size_t)b * N_PTS * 3;

    __shared__ v4f X4[RCHUNK / 4];
    __shared__ v4f Y4[RCHUNK / 4];
    __shared__ v4f Z4[RCHUNK / 4];
    __shared__ v4f W4[RCHUNK / 4];

    // stage + transform refs (consecutive t -> consecutive banks, no conflict)
    for (int t = tid; t < RCHUNK; t += BLK) {
        int ri = s * RCHUNK + t;
        float x = r[ri * 3 + 0];
        float y = r[ri * 3 + 1];
        float z = r[ri * 3 + 2];
        ((float*)X4)[t] = -2.0f * x;
        ((float*)Y4)[t] = -2.0f * y;
        ((float*)Z4)[t] = -2.0f * z;
        ((float*)W4)[t] = x * x + y * y + z * z;
    }

    // query register tile, duplicated into packed pairs for v_pk_fma_f32
    v2f qx2[QPT], qy2[QPT], qz2[QPT];
    float m[QPT];
    const int qbase = qc * QBLK + tid;
    #pragma unroll
    for (int j = 0; j < QPT; ++j) {
        int qi = qbase + j * BLK;
        float x = q[qi * 3 + 0];
        float y = q[qi * 3 + 1];
        float z = q[qi * 3 + 2];
        qx2[j] = (v2f){x, x};
        qy2[j] = (v2f){y, y};
        qz2[j] = (v2f){z, z};
        m[j]   = 3.4e38f;
    }

    __syncthreads();

    for (int k = 0; k < RCHUNK / 4; ++k) {
        v4f xv = X4[k];           // ds_read_b128: {x0,x1,x2,x3}
        v4f yv = Y4[k];
        v4f zv = Z4[k];
        v4f wv = W4[k];
        v2f x01 = xv.xy, x23 = xv.zw;   // register sub-pairs, no movs
        v2f y01 = yv.xy, y23 = yv.zw;
        v2f z01 = zv.xy, z23 = zv.zw;
        v2f w01 = wv.xy, w23 = wv.zw;

        #pragma unroll
        for (int j = 0; j < QPT; ++j) {
            v2f d01, d23;
            asm("v_pk_fma_f32 %0, %1, %2, %3"
                : "=v"(d01) : "v"(qz2[j]), "v"(z01), "v"(w01));
            asm("v_pk_fma_f32 %0, %1, %2, %0"
                : "+v"(d01) : "v"(qy2[j]), "v"(y01));
            asm("v_pk_fma_f32 %0, %1, %2, %0"
                : "+v"(d01) : "v"(qx2[j]), "v"(x01));
            asm("v_pk_fma_f32 %0, %1, %2, %3"
                : "=v"(d23) : "v"(qz2[j]), "v"(z23), "v"(w23));
            asm("v_pk_fma_f32 %0, %1, %2, %0"
                : "+v"(d23) : "v"(qy2[j]), "v"(y23));
            asm("v_pk_fma_f32 %0, %1, %2, %0"
                : "+v"(d23) : "v"(qx2[j]), "v"(x23));
            float t0 = fminf(fminf(d01.x, d01.y), d23.x);  // v_min3_f32
            m[j] = fminf(fminf(t0, d23.y), m[j]);          // v_min3_f32
        }
    }

    unsigned int* mb = minbuf + ((size_t)dir * 8 + b) * N_PTS;
    #pragma unroll
    for (int j = 0; j < QPT; ++j) {
        // order-preserving float->uint key (values may be negative pre-|q|^2)
        unsigned int bits = __float_as_uint(m[j]);
        unsigned int key  = bits ^ ((unsigned int)((int)bits >> 31) | 0x80000000u);
        atomicMin(&mb[qbase + j * BLK], key);
    }
}

// ---------------------------------------------------------------------------
// Stage 2: decode per-query min key, add |q|^2, reduce-sum into out.
// ---------------------------------------------------------------------------
__global__ __launch_bounds__(BLK) void chamfer_stage2(
    const float* __restrict__ preds,
    const float* __restrict__ gts,
    const unsigned int* __restrict__ minbuf,
    float* __restrict__ out)
{
    __shared__ float wsum[BLK / 64];
    const int tid = threadIdx.x;
    const int g   = blockIdx.x * BLK + tid;   // 0 .. 2*8*N_PTS-1
    const int dir = g >> 16;                   // 65536 queries per direction
    const int idx = g & 65535;                 // b*N_PTS + qi

    const float* q = ((dir == 0) ? gts : preds) + (size_t)idx * 3;
    float x = q[0], y = q[1], z = q[2];

    unsigned int key  = minbuf[g];
    unsigned int bits = (key & 0x80000000u) ? (key ^ 0x80000000u) : ~key;
    float val = __uint_as_float(bits) + (x * x + y * y + z * z);

    float sv = val;
    #pragma unroll
    for (int off = 32; off > 0; off >>= 1)
        sv += __shfl_down(sv, off, 64);

    if ((tid & 63) == 0) wsum[tid >> 6] = sv;
    __syncthreads();
    if (tid == 0) {
        float tot = 0.0f;
        #pragma unroll
        for (int w = 0; w < BLK / 64; ++w) tot += wsum[w];
        atomicAdd(out, tot);
    }
}

// ---------------------------------------------------------------------------
// Fallback (ws too small): LDS-tiled, 1 query/thread, no workspace needed.
// ---------------------------------------------------------------------------
__global__ __launch_bounds__(BLK) void chamfer_fallback(
    const float* __restrict__ preds,
    const float* __restrict__ gts,
    float* __restrict__ out)
{
    const int b   = blockIdx.y;
    const int dir = blockIdx.z;
    const float* q = ((dir == 0) ? gts   : preds) + (size_t)b * N_PTS * 3;
    const float* r = ((dir == 0) ? preds : gts)   + (size_t)b * N_PTS * 3;

    __shared__ float4 lds[1024];
    __shared__ float wsum[BLK / 64];

    const int tid = threadIdx.x;
    const int qi  = blockIdx.x * BLK + tid;
    const float qx = q[qi * 3 + 0];
    const float qy = q[qi * 3 + 1];
    const float qz = q[qi * 3 + 2];
    const float q2 = qx * qx + qy * qy + qz * qz;

    float best = 3.4e38f;
    for (int t0 = 0; t0 < N_PTS; t0 += 1024) {
        __syncthreads();
        for (int t = tid; t < 1024; t += BLK) {
            int ri = t0 + t;
            float x = r[ri * 3], y = r[ri * 3 + 1], z = r[ri * 3 + 2];
            lds[t] = make_float4(-2.f * x, -2.f * y, -2.f * z, x * x + y * y + z * z);
        }
        __syncthreads();
        for (int k = 0; k < 1024; ++k) {
            float4 rv = lds[k];
            best = fminf(best, fmaf(qx, rv.x, fmaf(qy, rv.y, fmaf(qz, rv.z, rv.w))));
        }
    }
    float sv = best + q2;
    #pragma unroll
    for (int off = 32; off > 0; off >>= 1)
        sv += __shfl_down(sv, off, 64);
    if ((tid & 63) == 0) wsum[tid >> 6] = sv;
    __syncthreads();
    if (tid == 0) {
        float tot = 0.0f;
        #pragma unroll
        for (int w = 0; w < BLK / 64; ++w) tot += wsum[w];
        atomicAdd(out, tot);
    }
}

extern "C" void kernel_launch(void* const* d_in, const int* in_sizes, int n_in,
                              void* d_out, int out_size, void* d_ws, size_t ws_size,
                              hipStream_t stream) {
    const float* preds = (const float*)d_in[0];
    const float* gts   = (const float*)d_in[1];
    float* out = (float*)d_out;

    const int B = 8;
    const size_t minbuf_bytes = (size_t)2 * B * N_PTS * sizeof(unsigned int); // 512 KB

    hipMemsetAsync(out, 0, sizeof(float), stream);

    if (ws_size >= minbuf_bytes) {
        unsigned int* minbuf = (unsigned int*)d_ws;
        hipMemsetAsync(minbuf, 0xFF, minbuf_bytes, stream);  // keys = UINT_MAX

        dim3 g1(2 * SPLITS, B, 2);   // 512 blocks, 2 per CU
        chamfer_stage1<<<g1, dim3(BLK), 0, stream>>>(preds, gts, minbuf);

        dim3 g2((2 * B * N_PTS) / BLK);  // 512 blocks
        chamfer_stage2<<<g2, dim3(BLK), 0, stream>>>(preds, gts, minbuf, out);
    } else {
        dim3 grid(N_PTS / BLK, B, 2);
        chamfer_fallback<<<grid, dim3(BLK), 0, stream>>>(preds, gts, out);
    }
}